// Round 10
// baseline (335.580 us; speedup 1.0000x reference)
//
#include <hip/hip_runtime.h>
#include <math.h>

#define LRELU 0.2f

constexpr int Bn = 32, Sn = 512, Hn = 768, Nn = 4096, En = 131072, Pn = 65536;
constexpr int ET = En + Nn;  // edges + self loops

typedef __attribute__((ext_vector_type(8))) short bf16x8;
typedef __attribute__((ext_vector_type(4))) float f32x4;

// ---------- workspace layout (float offsets) ----------
// UV bf16 [4096][3072] = 6291456 float-slots at 0, overlapping dead x0 (after
// GAT1 GEMM) and dead h1 (after agg1). SUV in dead-x1 region.
constexpr size_t OFF_X0  = 0;                      // 4096*768 fp32 (span feats)
constexpr size_t OFF_UV  = 0;                      // 4096*3072 bf16
constexpr size_t OFF_H1  = 4194304;                // 4096*512 bf16 (uses half)
constexpr size_t OFF_X1  = OFF_H1  + 2097152;      // 4096*512 fp32; SUV later (98304)
constexpr size_t OFF_H2  = OFF_X1  + 2097152;      // 4096*64; later UV-weight swizzle
constexpr size_t OFF_X2  = OFF_H2  + 262144;       // 4096*64
constexpr size_t OFF_ES1 = OFF_X2  + 262144;       // 4096*4
constexpr size_t OFF_ED1 = OFF_ES1 + 16384;
constexpr size_t OFF_ES2 = OFF_ED1 + 16384;        // 4096
constexpr size_t OFF_ED2 = OFF_ES2 + 4096;
constexpr size_t OFF_ROW = OFF_ED2 + 4096;         // int[4097]
constexpr size_t OFF_CUR = OFF_ROW + 4104;         // int[4096]
constexpr size_t OFF_EDG = OFF_CUR + 4096;         // int[135168]
constexpr size_t OFF_W1S = OFF_EDG + 135168;       // 768*512 bf16
constexpr size_t OFF_NW1S = OFF_W1S + 196608;      // 768*256 bf16
constexpr size_t OFF_W2S = OFF_NW1S + 98304;       // 512*64 bf16 = 16384 floats

__device__ __forceinline__ short f2bf(float f) {
  union { float f; unsigned u; } x; x.f = f;
  unsigned r = x.u + 0x7fff + ((x.u >> 16) & 1);   // RNE
  return (short)(r >> 16);
}
__device__ __forceinline__ float bf2f(short s) {
  union { unsigned u; float f; } x;
  x.u = ((unsigned)(unsigned short)s) << 16;
  return x.f;
}

// ---------------- span mean pooling ----------------
__global__ __launch_bounds__(256) void span_pool_k(
    const float* __restrict__ seq, const int* __restrict__ est,
    const int* __restrict__ eln, const int* __restrict__ ebt,
    float* __restrict__ x0) {
  int idx = blockIdx.x * 256 + threadIdx.x;
  if (idx >= Nn * (Hn / 4)) return;
  int e = idx / (Hn / 4);
  int c = (idx % (Hn / 4)) * 4;
  int s0 = est[e], L = eln[e] + 1, b = ebt[e];
  const float* p = seq + ((size_t)b * Sn + s0) * Hn + c;
  float ax = 0, ay = 0, az = 0, aw = 0;
  for (int i = 0; i < L; ++i) {
    float4 v = *(const float4*)(p + (size_t)i * Hn);
    ax += v.x; ay += v.y; az += v.z; aw += v.w;
  }
  float inv = 1.0f / (float)L;
  float4 o; o.x = ax * inv; o.y = ay * inv; o.z = az * inv; o.w = aw * inv;
  *(float4*)&x0[(size_t)e * Hn + c] = o;
}

// ---------------- MFMA bf16 GEMM: C[M,N] = A[M,K] @ Bswz ----------------
// EPI: 0 = fp32 store; 2 = bf16 store; 4 = bf16 store + rb1 fold on U half
template <int EPI, int NTW, int KC>
__global__ __launch_bounds__(256) void mfma_gemm_k(
    const float* __restrict__ A, const short* __restrict__ Bswz,
    float* __restrict__ C, const float* __restrict__ bias,
    int M, int K, int N) {
  constexpr int RS = KC + 8;
  __shared__ short at[64 * RS];
  int t = threadIdx.x;
  size_t rowb = (size_t)blockIdx.x * 64;
  int colb = blockIdx.y * (64 * NTW);
  int w = t >> 6, lane = t & 63, quad = lane >> 4, id = lane & 15;
  f32x4 acc[4][NTW];
#pragma unroll
  for (int mt = 0; mt < 4; ++mt)
#pragma unroll
    for (int nt = 0; nt < NTW; ++nt) acc[mt][nt] = (f32x4){0.f, 0.f, 0.f, 0.f};

  for (int k0 = 0; k0 < K; k0 += KC) {
    constexpr int CH = 64 * KC / 8 / 256;
#pragma unroll
    for (int i = 0; i < CH; ++i) {
      int cid = t + i * 256;
      int p = cid / (KC / 8), o8 = (cid % (KC / 8)) * 8;
      const float* src = &A[(rowb + p) * (size_t)K + k0 + o8];
      float4 v0 = *(const float4*)src;
      float4 v1 = *(const float4*)(src + 4);
      bf16x8 bv;
      bv[0] = f2bf(v0.x); bv[1] = f2bf(v0.y); bv[2] = f2bf(v0.z); bv[3] = f2bf(v0.w);
      bv[4] = f2bf(v1.x); bv[5] = f2bf(v1.y); bv[6] = f2bf(v1.z); bv[7] = f2bf(v1.w);
      *(bf16x8*)&at[p * RS + o8] = bv;
    }
    __syncthreads();
#pragma unroll
    for (int kk = 0; kk < KC / 32; ++kk) {
      bf16x8 af[4], bfr[NTW];
#pragma unroll
      for (int mt = 0; mt < 4; ++mt)
        af[mt] = *(const bf16x8*)&at[(mt * 16 + id) * RS + kk * 32 + quad * 8];
#pragma unroll
      for (int nt = 0; nt < NTW; ++nt) {
        int ntg = (colb >> 4) + w * NTW + nt;
        bfr[nt] = *(const bf16x8*)&Bswz[(((size_t)(k0 >> 5) + kk) * (N >> 4) + ntg) * 512 + lane * 8];
      }
#pragma unroll
      for (int mt = 0; mt < 4; ++mt)
#pragma unroll
        for (int nt = 0; nt < NTW; ++nt)
          acc[mt][nt] = __builtin_amdgcn_mfma_f32_16x16x32_bf16(af[mt], bfr[nt], acc[mt][nt], 0, 0, 0);
    }
    __syncthreads();
  }
#pragma unroll
  for (int nt = 0; nt < NTW; ++nt) {
    int col = colb + w * (16 * NTW) + nt * 16 + id;
#pragma unroll
    for (int mt = 0; mt < 4; ++mt) {
#pragma unroll
      for (int reg = 0; reg < 4; ++reg) {
        size_t row = rowb + mt * 16 + quad * 4 + reg;
        float v = acc[mt][nt][reg];
        if (EPI == 4) {
          int r = col >> 9, rem = col & 511;
          if (rem < 256) v += bias[(r << 8) + rem];   // fold rb1 into U half
          ((short*)C)[row * (size_t)N + col] = f2bf(v);
        } else if (EPI == 2) {
          ((short*)C)[row * (size_t)N + col] = f2bf(v);
        } else {
          C[row * (size_t)N + col] = v;
        }
      }
    }
  }
}

// ---------------- fused NER head ----------------
__global__ __launch_bounds__(256) void ner_fused_k(
    const float* __restrict__ A, const short* __restrict__ Bswz,
    const float* __restrict__ W2, const float* __restrict__ b1,
    const float* __restrict__ b2, float* __restrict__ out) {
  constexpr int K = 768;
  constexpr int RS = 136, HS = 264, WS = 260;
  __shared__ short at[64 * RS];
  __shared__ short hid[64 * HS];
  __shared__ float w2t[9 * WS];
  __shared__ float b2l[9];
  int t = threadIdx.x;
  size_t rowb = (size_t)blockIdx.x * 64;
  for (int u = t; u < 2304; u += 256) {
    int k = u / 9, jj = u % 9;
    w2t[jj * WS + k] = W2[u];
  }
  if (t < 9) b2l[t] = b2[t];
  int w = t >> 6, lane = t & 63, quad = lane >> 4, id = lane & 15;
  f32x4 acc[4][4];
#pragma unroll
  for (int mt = 0; mt < 4; ++mt)
#pragma unroll
    for (int nt = 0; nt < 4; ++nt) acc[mt][nt] = (f32x4){0.f, 0.f, 0.f, 0.f};

  for (int k0 = 0; k0 < K; k0 += 128) {
#pragma unroll
    for (int i = 0; i < 4; ++i) {
      int cid = t + i * 256;
      int p = cid >> 4, o8 = (cid & 15) * 8;
      const float* src = &A[(rowb + p) * (size_t)K + k0 + o8];
      float4 v0 = *(const float4*)src;
      float4 v1 = *(const float4*)(src + 4);
      bf16x8 bv;
      bv[0] = f2bf(v0.x); bv[1] = f2bf(v0.y); bv[2] = f2bf(v0.z); bv[3] = f2bf(v0.w);
      bv[4] = f2bf(v1.x); bv[5] = f2bf(v1.y); bv[6] = f2bf(v1.z); bv[7] = f2bf(v1.w);
      *(bf16x8*)&at[p * RS + o8] = bv;
    }
    __syncthreads();
#pragma unroll
    for (int kk = 0; kk < 4; ++kk) {
      bf16x8 af[4], bfr[4];
#pragma unroll
      for (int mt = 0; mt < 4; ++mt)
        af[mt] = *(const bf16x8*)&at[(mt * 16 + id) * RS + kk * 32 + quad * 8];
#pragma unroll
      for (int nt = 0; nt < 4; ++nt) {
        int ntg = w * 4 + nt;
        bfr[nt] = *(const bf16x8*)&Bswz[(((size_t)(k0 >> 5) + kk) * 16 + ntg) * 512 + lane * 8];
      }
#pragma unroll
      for (int mt = 0; mt < 4; ++mt)
#pragma unroll
        for (int nt = 0; nt < 4; ++nt)
          acc[mt][nt] = __builtin_amdgcn_mfma_f32_16x16x32_bf16(af[mt], bfr[nt], acc[mt][nt], 0, 0, 0);
    }
    __syncthreads();
  }
#pragma unroll
  for (int nt = 0; nt < 4; ++nt) {
    int col = w * 64 + nt * 16 + id;
    float bb = b1[col];
#pragma unroll
    for (int mt = 0; mt < 4; ++mt)
#pragma unroll
      for (int reg = 0; reg < 4; ++reg) {
        int row = mt * 16 + quad * 4 + reg;
        hid[row * HS + col] = f2bf(fmaxf(acc[mt][nt][reg] + bb, 0.f));
      }
  }
  __syncthreads();
  for (int u = t; u < 576; u += 256) {
    int row = u / 9, jj = u % 9;
    const short* hp = &hid[row * HS];
    const float* wp = &w2t[jj * WS];
    float a = 0.f;
#pragma unroll
    for (int k8 = 0; k8 < 256; k8 += 8) {
      bf16x8 hv = *(const bf16x8*)&hp[k8];
      float4 w0 = *(const float4*)&wp[k8];
      float4 w1 = *(const float4*)&wp[k8 + 4];
      a += bf2f(hv[0]) * w0.x + bf2f(hv[1]) * w0.y + bf2f(hv[2]) * w0.z + bf2f(hv[3]) * w0.w;
      a += bf2f(hv[4]) * w1.x + bf2f(hv[5]) * w1.y + bf2f(hv[6]) * w1.z + bf2f(hv[7]) * w1.w;
    }
    out[(rowb + row) * 9 + jj] = a + b2l[jj];
  }
}

// swizzle helper (fragment order)
__device__ __forceinline__ void swz_store(short* __restrict__ o, int k, int n, int N, float v) {
  int kk = k >> 5, quad = (k >> 3) & 3, j = k & 7, ntg = n >> 4, id = n & 15;
  o[(((size_t)kk * (N >> 4)) + ntg) * 512 + (quad * 16 + id) * 8 + j] = f2bf(v);
}

// merged start-time weight swizzles: W1 (768x512), nW1 (768x256), W2 (512x64)
__global__ void swz_all_k(const float* __restrict__ W1, const float* __restrict__ nW1,
                          const float* __restrict__ W2, short* __restrict__ w1s,
                          short* __restrict__ nw1s, short* __restrict__ w2s) {
  int i = blockIdx.x * 256 + threadIdx.x;
  if (i < 768 * 512) {
    swz_store(w1s, i / 512, i % 512, 512, W1[i]);
  } else if (i < 768 * 512 + 768 * 256) {
    int i2 = i - 768 * 512;
    swz_store(nw1s, i2 / 256, i2 % 256, 256, nW1[i2]);
  } else if (i < 768 * 512 + 768 * 256 + 512 * 64) {
    int i2 = i - (768 * 512 + 768 * 256);
    swz_store(w2s, i2 / 64, i2 % 64, 64, W2[i2]);
  }
}

// UV-weight swizzle: rW1[r][k][n] (6,128,256) -> combined B [K=64, N=3072]
__global__ void swz_uv_k(const float* __restrict__ rW1, short* __restrict__ o) {
  int i = blockIdx.x * 256 + threadIdx.x;
  if (i >= 6 * 128 * 256) return;
  int n = i & 255, k = (i >> 8) & 127, r = i >> 15;
  int c = r * 512 + (k >> 6) * 256 + n;
  int kr = k & 63;
  int kk = kr >> 5, quad = (kr >> 3) & 3, j = kr & 7, ntg = c >> 4, id = c & 15;
  o[(((size_t)kk * 192) + ntg) * 512 + (quad * 16 + id) * 8 + j] = f2bf(rW1[i]);
}

// ---------------- per-(node,r) U/V sums: SUV[node*6+r] = {su, su2, sv, sv2} ----------------
// block 256 = 4 waves; wave handles one (node,r): 64 lanes x 8 ch = 512 ch (U|V).
__global__ __launch_bounds__(256) void suv_k(const short* __restrict__ UV,
                                             float* __restrict__ SUV) {
  int t = threadIdx.x;
  int w = t >> 6, lane = t & 63;
  int idx = blockIdx.x * 4 + w;          // node*6 + r
  int node = idx / 6, r = idx - node * 6;
  bf16x8 x = *(const bf16x8*)&UV[(size_t)node * 3072 + r * 512 + lane * 8];
  float s = 0.f, s2 = 0.f;
#pragma unroll
  for (int k = 0; k < 8; ++k) { float f = bf2f(x[k]); s += f; s2 += f * f; }
#pragma unroll
  for (int off = 1; off < 32; off <<= 1) {
    s += __shfl_xor(s, off, 64);
    s2 += __shfl_xor(s2, off, 64);
  }
  if (lane == 0)  { SUV[idx * 4 + 0] = s; SUV[idx * 4 + 1] = s2; }
  if (lane == 32) { SUV[idx * 4 + 2] = s; SUV[idx * 4 + 3] = s2; }
}

// ---------------- attention coefficients (bf16 h) ----------------
template <int HD, int C>
__global__ __launch_bounds__(256) void coef_b_k(
    const short* __restrict__ h, const float* __restrict__ a_src,
    const float* __restrict__ a_dst, float* __restrict__ es, float* __restrict__ ed) {
  int idx = blockIdx.x * 256 + threadIdx.x;
  if (idx >= Nn * HD) return;
  int n = idx / HD, hd = idx % HD;
  const short* hp = h + (size_t)n * HD * C + hd * C;
  const float* sp = a_src + hd * C;
  const float* dp = a_dst + hd * C;
  float s = 0, d = 0;
  for (int c = 0; c < C; c += 8) {
    bf16x8 v = *(const bf16x8*)(hp + c);
#pragma unroll
    for (int k = 0; k < 8; ++k) {
      float f = bf2f(v[k]);
      s += f * sp[c + k];
      d += f * dp[c + k];
    }
  }
  es[idx] = s; ed[idx] = d;
}

// ---------------- CSR build (edges) ----------------
__global__ void zero_k(int* __restrict__ p, int n) {
  int i = blockIdx.x * 256 + threadIdx.x;
  if (i < n) p[i] = 0;
}

__global__ void count_k(const int* __restrict__ eidx, int* __restrict__ cnt) {
  int i = blockIdx.x * 256 + threadIdx.x;
  if (i >= ET) return;
  int dst = (i < En) ? eidx[En + i] : (i - En);
  atomicAdd(&cnt[dst], 1);
}

__global__ __launch_bounds__(256) void scan_k(int* cnt_cur, int* rowoff) {
  __shared__ int s[256];
  int t = threadIdx.x;
  int loc[16]; int run = 0; int base = t * 16;
#pragma unroll
  for (int i = 0; i < 16; ++i) { loc[i] = run; run += cnt_cur[base + i]; }
  s[t] = run;
  __syncthreads();
  for (int off = 1; off < 256; off <<= 1) {
    int v = (t >= off) ? s[t - off] : 0;
    __syncthreads();
    s[t] += v;
    __syncthreads();
  }
  int offset = (t > 0) ? s[t - 1] : 0;
#pragma unroll
  for (int i = 0; i < 16; ++i) {
    int o = offset + loc[i];
    rowoff[base + i] = o;
    cnt_cur[base + i] = o;
  }
  if (t == 255) rowoff[4096] = s[255];
}

__global__ void scatter_k(const int* __restrict__ eidx, int* __restrict__ cur,
                          int* __restrict__ esrc) {
  int i = blockIdx.x * 256 + threadIdx.x;
  if (i >= ET) return;
  int s, d;
  if (i < En) { s = eidx[i]; d = eidx[En + i]; } else { s = d = i - En; }
  int pos = atomicAdd(&cur[d], 1);
  esrc[pos] = s;
}

// ---------------- GAT softmax-aggregate, bf16 h, row-coalesced pass 3 ----------------
template <int HD, int C, bool RELU>
__global__ __launch_bounds__(256) void gat_agg_k(
    const short* __restrict__ h, const float* __restrict__ es,
    const float* __restrict__ ed, const int* __restrict__ row_off,
    const int* __restrict__ eslist, const float* __restrict__ bias,
    float* __restrict__ xout) {
  constexpr int HDC = HD * C, OCT = HDC / 8, JS = 256 / OCT;
  constexpr int CAP = 320;
  __shared__ float red[256];
  __shared__ float mxs[HD], dns[HD];
  __shared__ float exc[CAP * HD];
  __shared__ float part[JS * HDC];
  int n = blockIdx.x, t = threadIdx.x;
  int ro = row_off[n], deg = row_off[n + 1] - ro;
  int hd = t % HD, ei = t / HD;
  constexpr int ES = 256 / HD;
  float edv = ed[n * HD + hd];
  float pm = -3.402823466e38f;
  for (int j = ei; j < deg; j += ES) {
    int s = eslist[ro + j];
    float e = es[s * HD + hd] + edv;
    e = (e > 0.f) ? e : LRELU * e;
    pm = fmaxf(pm, e);
  }
  red[t] = pm;
  __syncthreads();
  for (int off = 128; off >= HD; off >>= 1) {
    if (t < off) red[t] = fmaxf(red[t], red[t + off]);
    __syncthreads();
  }
  if (t < HD) mxs[t] = red[t];
  __syncthreads();
  float mx = mxs[hd];
  float ps = 0.f;
  for (int j = ei; j < deg; j += ES) {
    int s = eslist[ro + j];
    float e = es[s * HD + hd] + edv;
    e = (e > 0.f) ? e : LRELU * e;
    float ex = __expf(e - mx);
    if (j < CAP) exc[j * HD + hd] = ex;
    ps += ex;
  }
  red[t] = ps;
  __syncthreads();
  for (int off = 128; off >= HD; off >>= 1) {
    if (t < off) red[t] += red[t + off];
    __syncthreads();
  }
  if (t < HD) dns[t] = red[t];
  __syncthreads();
  int oc = t % OCT, js = t / OCT;
  int hh = oc / (C / 8);
  float mxh = mxs[hh], edh = ed[n * HD + hh];
  float a[8];
#pragma unroll
  for (int k = 0; k < 8; ++k) a[k] = 0.f;
  for (int j = js; j < deg; j += JS) {
    int s = eslist[ro + j];
    float ex;
    if (j < CAP) ex = exc[j * HD + hh];
    else {
      float e = es[s * HD + hh] + edh;
      e = (e > 0.f) ? e : LRELU * e;
      ex = __expf(e - mxh);
    }
    bf16x8 hv = *(const bf16x8*)&h[(size_t)s * HDC + oc * 8];
#pragma unroll
    for (int k = 0; k < 8; ++k) a[k] += ex * bf2f(hv[k]);
  }
#pragma unroll
  for (int k = 0; k < 8; ++k) part[js * HDC + oc * 8 + k] = a[k];
  __syncthreads();
  for (int c = t; c < HDC; c += 256) {
    float sum = 0.f;
#pragma unroll
    for (int q = 0; q < JS; ++q) sum += part[q * HDC + c];
    int hh2 = c / C;
    float v = sum / dns[hh2] + bias[c];
    if (RELU) v = fmaxf(v, 0.f);
    xout[(size_t)n * HDC + c] = v;
  }
}

// ---------------- pair relation head (pipelined, precomputed sums) ----------------
// UV bf16 [node][3072] (per node: 6 r x (U 256 | V 256)); U includes rb1.
// SUV[node*6+r] = {su, su2, sv, sv2}. s1 = su+sv; s2 = su2+sv2+2*dot(u,v).
// grid (P/128, 6); block 256 = 4 waves; 16-lane group per pair, 8 iters, prefetched.
__global__ __launch_bounds__(256) void pair_rel_k(
    const short* __restrict__ UV, const float* __restrict__ SUV,
    const int* __restrict__ pidx, const float* __restrict__ lng,
    const float* __restrict__ lnb, const float* __restrict__ rW2,
    const float* __restrict__ rb2, float* __restrict__ out) {
  int t = threadIdx.x;
  int r = blockIdx.y;
  int w = t >> 6, lane = t & 63;
  int pg = lane >> 4, l16 = lane & 15;
  float g[16], bb[16], wv[16];
  int cb = r * 256 + l16 * 16;
#pragma unroll
  for (int q = 0; q < 4; ++q) {
    *(float4*)&g[q * 4]  = *(const float4*)&lng[cb + q * 4];
    *(float4*)&bb[q * 4] = *(const float4*)&lnb[cb + q * 4];
    *(float4*)&wv[q * 4] = *(const float4*)&rW2[cb + q * 4];
  }
  float rb2v = rb2[r];
  size_t roff = (size_t)r * 512 + l16 * 16;
  int pbase = blockIdx.x * 128 + w * 32;
  // prefetch iteration 0
  int p = pbase + pg;
  int2 ij = *(const int2*)&pidx[2 * p];
  const short* up = &UV[(size_t)ij.x * 3072 + roff];
  const short* vp = &UV[(size_t)ij.y * 3072 + roff + 256];
  bf16x8 u0 = *(const bf16x8*)up, u1 = *(const bf16x8*)(up + 8);
  bf16x8 v0 = *(const bf16x8*)vp, v1 = *(const bf16x8*)(vp + 8);
  float2 sU = *(const float2*)&SUV[(ij.x * 6 + r) * 4];
  float2 sV = *(const float2*)&SUV[(ij.y * 6 + r) * 4 + 2];
#pragma unroll
  for (int it = 0; it < 8; ++it) {
    bf16x8 cu0 = u0, cu1 = u1, cv0 = v0, cv1 = v1;
    float2 csU = sU, csV = sV;
    int cp = p;
    if (it < 7) {
      p = pbase + (it + 1) * 4 + pg;
      ij = *(const int2*)&pidx[2 * p];
      up = &UV[(size_t)ij.x * 3072 + roff];
      vp = &UV[(size_t)ij.y * 3072 + roff + 256];
      u0 = *(const bf16x8*)up; u1 = *(const bf16x8*)(up + 8);
      v0 = *(const bf16x8*)vp; v1 = *(const bf16x8*)(vp + 8);
      sU = *(const float2*)&SUV[(ij.x * 6 + r) * 4];
      sV = *(const float2*)&SUV[(ij.y * 6 + r) * 4 + 2];
    }
    float hv[16], dotp = 0.f;
#pragma unroll
    for (int cc = 0; cc < 8; ++cc) {
      float uu = bf2f(cu0[cc]), vv = bf2f(cv0[cc]);
      hv[cc] = uu + vv;
      dotp += uu * vv;
    }
#pragma unroll
    for (int cc = 0; cc < 8; ++cc) {
      float uu = bf2f(cu1[cc]), vv = bf2f(cv1[cc]);
      hv[8 + cc] = uu + vv;
      dotp += uu * vv;
    }
#pragma unroll
    for (int off = 1; off < 16; off <<= 1) dotp += __shfl_xor(dotp, off, 64);
    float s1 = csU.x + csV.x;
    float s2 = csU.y + csV.y + 2.f * dotp;
    float mu = s1 * (1.f / 256.f);
    float var = s2 * (1.f / 256.f) - mu * mu;
    float rs = rsqrtf(var + 1e-5f);
    float pv = 0.f;
#pragma unroll
    for (int cc = 0; cc < 16; ++cc) {
      float v = (hv[cc] - mu) * rs * g[cc] + bb[cc];
      v = fmaxf(v, 0.f);
      pv += v * wv[cc];
    }
#pragma unroll
    for (int off = 1; off < 16; off <<= 1) pv += __shfl_xor(pv, off, 64);
    if (l16 == 0) out[(size_t)r * Pn + cp] = pv + rb2v;
  }
}

extern "C" void kernel_launch(void* const* d_in, const int* in_sizes, int n_in,
                              void* d_out, int out_size, void* d_ws, size_t ws_size,
                              hipStream_t stream) {
  const float* seq = (const float*)d_in[0];
  const int* est = (const int*)d_in[1];
  const int* eln = (const int*)d_in[2];
  const int* ebt = (const int*)d_in[3];
  const int* eidx = (const int*)d_in[4];
  const int* pidx = (const int*)d_in[5];
  const float* W1 = (const float*)d_in[6];
  const float* as1 = (const float*)d_in[7];
  const float* ad1 = (const float*)d_in[8];
  const float* b1 = (const float*)d_in[9];
  const float* W2 = (const float*)d_in[10];
  const float* as2 = (const float*)d_in[11];
  const float* ad2 = (const float*)d_in[12];
  const float* b2 = (const float*)d_in[13];
  const float* rW1 = (const float*)d_in[14];
  const float* rb1 = (const float*)d_in[15];
  const float* lng = (const float*)d_in[16];
  const float* lnb = (const float*)d_in[17];
  const float* rW2 = (const float*)d_in[18];
  const float* rb2 = (const float*)d_in[19];
  const float* nW1 = (const float*)d_in[20];
  const float* nb1 = (const float*)d_in[21];
  const float* nW2 = (const float*)d_in[22];
  const float* nb2 = (const float*)d_in[23];
  float* out = (float*)d_out;
  float* ws = (float*)d_ws;

  float* x0 = ws + OFF_X0;
  short* uv = (short*)(ws + OFF_UV);
  short* h1 = (short*)(ws + OFF_H1);
  float* x1 = ws + OFF_X1;
  float* suv = ws + OFF_X1;             // after GAT2 GEMM, x1 region reused
  short* h2 = (short*)(ws + OFF_H2);
  short* uvw = (short*)(ws + OFF_H2);   // after agg2/coef2, h2 region reused
  float* x2 = ws + OFF_X2;
  float* es1 = ws + OFF_ES1;
  float* ed1 = ws + OFF_ED1;
  float* es2 = ws + OFF_ES2;
  float* ed2 = ws + OFF_ED2;
  int* rowoff = (int*)(ws + OFF_ROW);
  int* cur = (int*)(ws + OFF_CUR);
  int* edg = (int*)(ws + OFF_EDG);
  short* w1s = (short*)(ws + OFF_W1S);
  short* nw1s = (short*)(ws + OFF_NW1S);
  short* w2s = (short*)(ws + OFF_W2S);

  // edge CSR build + merged weight swizzles
  zero_k<<<16, 256, 0, stream>>>(cur, Nn);
  count_k<<<(ET + 255) / 256, 256, 0, stream>>>(eidx, cur);
  scan_k<<<1, 256, 0, stream>>>(cur, rowoff);
  scatter_k<<<(ET + 255) / 256, 256, 0, stream>>>(eidx, cur, edg);
  swz_all_k<<<(768 * 512 + 768 * 256 + 512 * 64 + 255) / 256, 256, 0, stream>>>(
      W1, nW1, W2, w1s, nw1s, w2s);

  // entity features
  span_pool_k<<<Nn * (Hn / 4) / 256, 256, 0, stream>>>(seq, est, eln, ebt, x0);

  // GAT layer 1 (MFMA bf16, bf16 h1 out)
  mfma_gemm_k<2, 2, 128><<<dim3(Nn / 64, 512 / 128), 256, 0, stream>>>(x0, w1s, (float*)h1, nullptr, Nn, Hn, 512);
  coef_b_k<4, 128><<<(Nn * 4) / 256, 256, 0, stream>>>(h1, as1, ad1, es1, ed1);
  gat_agg_k<4, 128, true><<<Nn, 256, 0, stream>>>(h1, es1, ed1, rowoff, edg, b1, x1);

  // GAT layer 2 (MFMA bf16, bf16 h2 out); x1 dead afterwards
  mfma_gemm_k<2, 1, 128><<<dim3(Nn / 64, 1), 256, 0, stream>>>(x1, w2s, (float*)h2, nullptr, Nn, 512, 64);
  coef_b_k<1, 64><<<(Nn + 255) / 256, 256, 0, stream>>>(h2, as2, ad2, es2, ed2);
  gat_agg_k<1, 64, false><<<Nn, 256, 0, stream>>>(h2, es2, ed2, rowoff, edg, b2, x2);

  // relation head: U/V node GEMM (+rb1 on U), per-(node,r) sums, pair epilogue
  swz_uv_k<<<(6 * 128 * 256) / 256, 256, 0, stream>>>(rW1, uvw);
  mfma_gemm_k<4, 2, 64><<<dim3(Nn / 64, 3072 / 128), 256, 0, stream>>>(x2, uvw, (float*)uv, rb1, Nn, 64, 3072);
  suv_k<<<(Nn * 6) / 4, 256, 0, stream>>>(uv, suv);
  pair_rel_k<<<dim3(Pn / 128, 6), 256, 0, stream>>>(uv, suv, pidx, lng, lnb, rW2, rb2,
                                                    out + (size_t)Bn * Sn * 9);

  // fused NER head -> out[0 .. 147455]
  ner_fused_k<<<(Bn * Sn) / 64, 256, 0, stream>>>(seq, nw1s, nW2, nb1, nb2, out);
}

// Round 11
// 332.179 us; speedup vs baseline: 1.0102x; 1.0102x over previous
//
#include <hip/hip_runtime.h>
#include <math.h>

#define LRELU 0.2f

constexpr int Bn = 32, Sn = 512, Hn = 768, Nn = 4096, En = 131072, Pn = 65536;
constexpr int ET = En + Nn;  // edges + self loops

typedef __attribute__((ext_vector_type(8))) short bf16x8;
typedef __attribute__((ext_vector_type(4))) float f32x4;

// ---------- workspace layout (float offsets) ----------
// UV bf16 [4096][3072] = 6291456 float-slots at 0, overlapping dead x0 (after
// GAT1 GEMM) and dead h1 (after agg1).
constexpr size_t OFF_X0  = 0;                      // 4096*768 fp32 (span feats)
constexpr size_t OFF_UV  = 0;                      // 4096*3072 bf16
constexpr size_t OFF_H1  = 4194304;                // 4096*512 bf16 (uses half)
constexpr size_t OFF_X1  = OFF_H1  + 2097152;      // 4096*512 fp32
constexpr size_t OFF_H2  = OFF_X1  + 2097152;      // 4096*64; later UV-weight swizzle
constexpr size_t OFF_X2  = OFF_H2  + 262144;       // 4096*64
constexpr size_t OFF_ES1 = OFF_X2  + 262144;       // 4096*4
constexpr size_t OFF_ED1 = OFF_ES1 + 16384;
constexpr size_t OFF_ES2 = OFF_ED1 + 16384;        // 4096
constexpr size_t OFF_ED2 = OFF_ES2 + 4096;
constexpr size_t OFF_ROW = OFF_ED2 + 4096;         // int[4097]
constexpr size_t OFF_CUR = OFF_ROW + 4104;         // int[4096]
constexpr size_t OFF_EDG = OFF_CUR + 4096;         // int[135168]
constexpr size_t OFF_W1S = OFF_EDG + 135168;       // 768*512 bf16
constexpr size_t OFF_NW1S = OFF_W1S + 196608;      // 768*256 bf16
constexpr size_t OFF_W2S = OFF_NW1S + 98304;       // 512*64 bf16 = 16384 floats

__device__ __forceinline__ short f2bf(float f) {
  union { float f; unsigned u; } x; x.f = f;
  unsigned r = x.u + 0x7fff + ((x.u >> 16) & 1);   // RNE
  return (short)(r >> 16);
}
__device__ __forceinline__ float bf2f(short s) {
  union { unsigned u; float f; } x;
  x.u = ((unsigned)(unsigned short)s) << 16;
  return x.f;
}

// ---------------- span mean pooling ----------------
__global__ __launch_bounds__(256) void span_pool_k(
    const float* __restrict__ seq, const int* __restrict__ est,
    const int* __restrict__ eln, const int* __restrict__ ebt,
    float* __restrict__ x0) {
  int idx = blockIdx.x * 256 + threadIdx.x;
  if (idx >= Nn * (Hn / 4)) return;
  int e = idx / (Hn / 4);
  int c = (idx % (Hn / 4)) * 4;
  int s0 = est[e], L = eln[e] + 1, b = ebt[e];
  const float* p = seq + ((size_t)b * Sn + s0) * Hn + c;
  float ax = 0, ay = 0, az = 0, aw = 0;
  for (int i = 0; i < L; ++i) {
    float4 v = *(const float4*)(p + (size_t)i * Hn);
    ax += v.x; ay += v.y; az += v.z; aw += v.w;
  }
  float inv = 1.0f / (float)L;
  float4 o; o.x = ax * inv; o.y = ay * inv; o.z = az * inv; o.w = aw * inv;
  *(float4*)&x0[(size_t)e * Hn + c] = o;
}

// ---------------- MFMA bf16 GEMM: C[M,N] = A[M,K] @ Bswz ----------------
// EPI: 0 = fp32 store; 2 = bf16 store; 4 = bf16 store + rb1 fold on U half
template <int EPI, int NTW, int KC>
__global__ __launch_bounds__(256) void mfma_gemm_k(
    const float* __restrict__ A, const short* __restrict__ Bswz,
    float* __restrict__ C, const float* __restrict__ bias,
    int M, int K, int N) {
  constexpr int RS = KC + 8;
  __shared__ short at[64 * RS];
  int t = threadIdx.x;
  size_t rowb = (size_t)blockIdx.x * 64;
  int colb = blockIdx.y * (64 * NTW);
  int w = t >> 6, lane = t & 63, quad = lane >> 4, id = lane & 15;
  f32x4 acc[4][NTW];
#pragma unroll
  for (int mt = 0; mt < 4; ++mt)
#pragma unroll
    for (int nt = 0; nt < NTW; ++nt) acc[mt][nt] = (f32x4){0.f, 0.f, 0.f, 0.f};

  for (int k0 = 0; k0 < K; k0 += KC) {
    constexpr int CH = 64 * KC / 8 / 256;
#pragma unroll
    for (int i = 0; i < CH; ++i) {
      int cid = t + i * 256;
      int p = cid / (KC / 8), o8 = (cid % (KC / 8)) * 8;
      const float* src = &A[(rowb + p) * (size_t)K + k0 + o8];
      float4 v0 = *(const float4*)src;
      float4 v1 = *(const float4*)(src + 4);
      bf16x8 bv;
      bv[0] = f2bf(v0.x); bv[1] = f2bf(v0.y); bv[2] = f2bf(v0.z); bv[3] = f2bf(v0.w);
      bv[4] = f2bf(v1.x); bv[5] = f2bf(v1.y); bv[6] = f2bf(v1.z); bv[7] = f2bf(v1.w);
      *(bf16x8*)&at[p * RS + o8] = bv;
    }
    __syncthreads();
#pragma unroll
    for (int kk = 0; kk < KC / 32; ++kk) {
      bf16x8 af[4], bfr[NTW];
#pragma unroll
      for (int mt = 0; mt < 4; ++mt)
        af[mt] = *(const bf16x8*)&at[(mt * 16 + id) * RS + kk * 32 + quad * 8];
#pragma unroll
      for (int nt = 0; nt < NTW; ++nt) {
        int ntg = (colb >> 4) + w * NTW + nt;
        bfr[nt] = *(const bf16x8*)&Bswz[(((size_t)(k0 >> 5) + kk) * (N >> 4) + ntg) * 512 + lane * 8];
      }
#pragma unroll
      for (int mt = 0; mt < 4; ++mt)
#pragma unroll
        for (int nt = 0; nt < NTW; ++nt)
          acc[mt][nt] = __builtin_amdgcn_mfma_f32_16x16x32_bf16(af[mt], bfr[nt], acc[mt][nt], 0, 0, 0);
    }
    __syncthreads();
  }
#pragma unroll
  for (int nt = 0; nt < NTW; ++nt) {
    int col = colb + w * (16 * NTW) + nt * 16 + id;
#pragma unroll
    for (int mt = 0; mt < 4; ++mt) {
#pragma unroll
      for (int reg = 0; reg < 4; ++reg) {
        size_t row = rowb + mt * 16 + quad * 4 + reg;
        float v = acc[mt][nt][reg];
        if (EPI == 4) {
          int r = col >> 9, rem = col & 511;
          if (rem < 256) v += bias[(r << 8) + rem];   // fold rb1 into U half
          ((short*)C)[row * (size_t)N + col] = f2bf(v);
        } else if (EPI == 2) {
          ((short*)C)[row * (size_t)N + col] = f2bf(v);
        } else {
          C[row * (size_t)N + col] = v;
        }
      }
    }
  }
}

// ---------------- fused NER head ----------------
__global__ __launch_bounds__(256) void ner_fused_k(
    const float* __restrict__ A, const short* __restrict__ Bswz,
    const float* __restrict__ W2, const float* __restrict__ b1,
    const float* __restrict__ b2, float* __restrict__ out) {
  constexpr int K = 768;
  constexpr int RS = 136, HS = 264, WS = 260;
  __shared__ short at[64 * RS];
  __shared__ short hid[64 * HS];
  __shared__ float w2t[9 * WS];
  __shared__ float b2l[9];
  int t = threadIdx.x;
  size_t rowb = (size_t)blockIdx.x * 64;
  for (int u = t; u < 2304; u += 256) {
    int k = u / 9, jj = u % 9;
    w2t[jj * WS + k] = W2[u];
  }
  if (t < 9) b2l[t] = b2[t];
  int w = t >> 6, lane = t & 63, quad = lane >> 4, id = lane & 15;
  f32x4 acc[4][4];
#pragma unroll
  for (int mt = 0; mt < 4; ++mt)
#pragma unroll
    for (int nt = 0; nt < 4; ++nt) acc[mt][nt] = (f32x4){0.f, 0.f, 0.f, 0.f};

  for (int k0 = 0; k0 < K; k0 += 128) {
#pragma unroll
    for (int i = 0; i < 4; ++i) {
      int cid = t + i * 256;
      int p = cid >> 4, o8 = (cid & 15) * 8;
      const float* src = &A[(rowb + p) * (size_t)K + k0 + o8];
      float4 v0 = *(const float4*)src;
      float4 v1 = *(const float4*)(src + 4);
      bf16x8 bv;
      bv[0] = f2bf(v0.x); bv[1] = f2bf(v0.y); bv[2] = f2bf(v0.z); bv[3] = f2bf(v0.w);
      bv[4] = f2bf(v1.x); bv[5] = f2bf(v1.y); bv[6] = f2bf(v1.z); bv[7] = f2bf(v1.w);
      *(bf16x8*)&at[p * RS + o8] = bv;
    }
    __syncthreads();
#pragma unroll
    for (int kk = 0; kk < 4; ++kk) {
      bf16x8 af[4], bfr[4];
#pragma unroll
      for (int mt = 0; mt < 4; ++mt)
        af[mt] = *(const bf16x8*)&at[(mt * 16 + id) * RS + kk * 32 + quad * 8];
#pragma unroll
      for (int nt = 0; nt < 4; ++nt) {
        int ntg = w * 4 + nt;
        bfr[nt] = *(const bf16x8*)&Bswz[(((size_t)(k0 >> 5) + kk) * 16 + ntg) * 512 + lane * 8];
      }
#pragma unroll
      for (int mt = 0; mt < 4; ++mt)
#pragma unroll
        for (int nt = 0; nt < 4; ++nt)
          acc[mt][nt] = __builtin_amdgcn_mfma_f32_16x16x32_bf16(af[mt], bfr[nt], acc[mt][nt], 0, 0, 0);
    }
    __syncthreads();
  }
#pragma unroll
  for (int nt = 0; nt < 4; ++nt) {
    int col = w * 64 + nt * 16 + id;
    float bb = b1[col];
#pragma unroll
    for (int mt = 0; mt < 4; ++mt)
#pragma unroll
      for (int reg = 0; reg < 4; ++reg) {
        int row = mt * 16 + quad * 4 + reg;
        hid[row * HS + col] = f2bf(fmaxf(acc[mt][nt][reg] + bb, 0.f));
      }
  }
  __syncthreads();
  for (int u = t; u < 576; u += 256) {
    int row = u / 9, jj = u % 9;
    const short* hp = &hid[row * HS];
    const float* wp = &w2t[jj * WS];
    float a = 0.f;
#pragma unroll
    for (int k8 = 0; k8 < 256; k8 += 8) {
      bf16x8 hv = *(const bf16x8*)&hp[k8];
      float4 w0 = *(const float4*)&wp[k8];
      float4 w1 = *(const float4*)&wp[k8 + 4];
      a += bf2f(hv[0]) * w0.x + bf2f(hv[1]) * w0.y + bf2f(hv[2]) * w0.z + bf2f(hv[3]) * w0.w;
      a += bf2f(hv[4]) * w1.x + bf2f(hv[5]) * w1.y + bf2f(hv[6]) * w1.z + bf2f(hv[7]) * w1.w;
    }
    out[(rowb + row) * 9 + jj] = a + b2l[jj];
  }
}

// swizzle helper (fragment order)
__device__ __forceinline__ void swz_store(short* __restrict__ o, int k, int n, int N, float v) {
  int kk = k >> 5, quad = (k >> 3) & 3, j = k & 7, ntg = n >> 4, id = n & 15;
  o[(((size_t)kk * (N >> 4)) + ntg) * 512 + (quad * 16 + id) * 8 + j] = f2bf(v);
}

// merged start-time weight swizzles: W1 (768x512), nW1 (768x256), W2 (512x64)
__global__ void swz_all_k(const float* __restrict__ W1, const float* __restrict__ nW1,
                          const float* __restrict__ W2, short* __restrict__ w1s,
                          short* __restrict__ nw1s, short* __restrict__ w2s) {
  int i = blockIdx.x * 256 + threadIdx.x;
  if (i < 768 * 512) {
    swz_store(w1s, i / 512, i % 512, 512, W1[i]);
  } else if (i < 768 * 512 + 768 * 256) {
    int i2 = i - 768 * 512;
    swz_store(nw1s, i2 / 256, i2 % 256, 256, nW1[i2]);
  } else if (i < 768 * 512 + 768 * 256 + 512 * 64) {
    int i2 = i - (768 * 512 + 768 * 256);
    swz_store(w2s, i2 / 64, i2 % 64, 64, W2[i2]);
  }
}

// UV-weight swizzle: rW1[r][k][n] (6,128,256) -> combined B [K=64, N=3072]
__global__ void swz_uv_k(const float* __restrict__ rW1, short* __restrict__ o) {
  int i = blockIdx.x * 256 + threadIdx.x;
  if (i >= 6 * 128 * 256) return;
  int n = i & 255, k = (i >> 8) & 127, r = i >> 15;
  int c = r * 512 + (k >> 6) * 256 + n;
  int kr = k & 63;
  int kk = kr >> 5, quad = (kr >> 3) & 3, j = kr & 7, ntg = c >> 4, id = c & 15;
  o[(((size_t)kk * 192) + ntg) * 512 + (quad * 16 + id) * 8 + j] = f2bf(rW1[i]);
}

// ---------------- attention coefficients (bf16 h) ----------------
template <int HD, int C>
__global__ __launch_bounds__(256) void coef_b_k(
    const short* __restrict__ h, const float* __restrict__ a_src,
    const float* __restrict__ a_dst, float* __restrict__ es, float* __restrict__ ed) {
  int idx = blockIdx.x * 256 + threadIdx.x;
  if (idx >= Nn * HD) return;
  int n = idx / HD, hd = idx % HD;
  const short* hp = h + (size_t)n * HD * C + hd * C;
  const float* sp = a_src + hd * C;
  const float* dp = a_dst + hd * C;
  float s = 0, d = 0;
  for (int c = 0; c < C; c += 8) {
    bf16x8 v = *(const bf16x8*)(hp + c);
#pragma unroll
    for (int k = 0; k < 8; ++k) {
      float f = bf2f(v[k]);
      s += f * sp[c + k];
      d += f * dp[c + k];
    }
  }
  es[idx] = s; ed[idx] = d;
}

// ---------------- CSR build (edges) ----------------
__global__ void zero_k(int* __restrict__ p, int n) {
  int i = blockIdx.x * 256 + threadIdx.x;
  if (i < n) p[i] = 0;
}

__global__ void count_k(const int* __restrict__ eidx, int* __restrict__ cnt) {
  int i = blockIdx.x * 256 + threadIdx.x;
  if (i >= ET) return;
  int dst = (i < En) ? eidx[En + i] : (i - En);
  atomicAdd(&cnt[dst], 1);
}

__global__ __launch_bounds__(256) void scan_k(int* cnt_cur, int* rowoff) {
  __shared__ int s[256];
  int t = threadIdx.x;
  int loc[16]; int run = 0; int base = t * 16;
#pragma unroll
  for (int i = 0; i < 16; ++i) { loc[i] = run; run += cnt_cur[base + i]; }
  s[t] = run;
  __syncthreads();
  for (int off = 1; off < 256; off <<= 1) {
    int v = (t >= off) ? s[t - off] : 0;
    __syncthreads();
    s[t] += v;
    __syncthreads();
  }
  int offset = (t > 0) ? s[t - 1] : 0;
#pragma unroll
  for (int i = 0; i < 16; ++i) {
    int o = offset + loc[i];
    rowoff[base + i] = o;
    cnt_cur[base + i] = o;
  }
  if (t == 255) rowoff[4096] = s[255];
}

__global__ void scatter_k(const int* __restrict__ eidx, int* __restrict__ cur,
                          int* __restrict__ esrc) {
  int i = blockIdx.x * 256 + threadIdx.x;
  if (i >= ET) return;
  int s, d;
  if (i < En) { s = eidx[i]; d = eidx[En + i]; } else { s = d = i - En; }
  int pos = atomicAdd(&cur[d], 1);
  esrc[pos] = s;
}

// ---------------- GAT softmax-aggregate, bf16 h, row-coalesced pass 3 ----------------
template <int HD, int C, bool RELU>
__global__ __launch_bounds__(256) void gat_agg_k(
    const short* __restrict__ h, const float* __restrict__ es,
    const float* __restrict__ ed, const int* __restrict__ row_off,
    const int* __restrict__ eslist, const float* __restrict__ bias,
    float* __restrict__ xout) {
  constexpr int HDC = HD * C, OCT = HDC / 8, JS = 256 / OCT;
  constexpr int CAP = 320;
  __shared__ float red[256];
  __shared__ float mxs[HD], dns[HD];
  __shared__ float exc[CAP * HD];
  __shared__ float part[JS * HDC];
  int n = blockIdx.x, t = threadIdx.x;
  int ro = row_off[n], deg = row_off[n + 1] - ro;
  int hd = t % HD, ei = t / HD;
  constexpr int ES = 256 / HD;
  float edv = ed[n * HD + hd];
  float pm = -3.402823466e38f;
  for (int j = ei; j < deg; j += ES) {
    int s = eslist[ro + j];
    float e = es[s * HD + hd] + edv;
    e = (e > 0.f) ? e : LRELU * e;
    pm = fmaxf(pm, e);
  }
  red[t] = pm;
  __syncthreads();
  for (int off = 128; off >= HD; off >>= 1) {
    if (t < off) red[t] = fmaxf(red[t], red[t + off]);
    __syncthreads();
  }
  if (t < HD) mxs[t] = red[t];
  __syncthreads();
  float mx = mxs[hd];
  float ps = 0.f;
  for (int j = ei; j < deg; j += ES) {
    int s = eslist[ro + j];
    float e = es[s * HD + hd] + edv;
    e = (e > 0.f) ? e : LRELU * e;
    float ex = __expf(e - mx);
    if (j < CAP) exc[j * HD + hd] = ex;
    ps += ex;
  }
  red[t] = ps;
  __syncthreads();
  for (int off = 128; off >= HD; off >>= 1) {
    if (t < off) red[t] += red[t + off];
    __syncthreads();
  }
  if (t < HD) dns[t] = red[t];
  __syncthreads();
  int oc = t % OCT, js = t / OCT;
  int hh = oc / (C / 8);
  float mxh = mxs[hh], edh = ed[n * HD + hh];
  float a[8];
#pragma unroll
  for (int k = 0; k < 8; ++k) a[k] = 0.f;
  for (int j = js; j < deg; j += JS) {
    int s = eslist[ro + j];
    float ex;
    if (j < CAP) ex = exc[j * HD + hh];
    else {
      float e = es[s * HD + hh] + edh;
      e = (e > 0.f) ? e : LRELU * e;
      ex = __expf(e - mxh);
    }
    bf16x8 hv = *(const bf16x8*)&h[(size_t)s * HDC + oc * 8];
#pragma unroll
    for (int k = 0; k < 8; ++k) a[k] += ex * bf2f(hv[k]);
  }
#pragma unroll
  for (int k = 0; k < 8; ++k) part[js * HDC + oc * 8 + k] = a[k];
  __syncthreads();
  for (int c = t; c < HDC; c += 256) {
    float sum = 0.f;
#pragma unroll
    for (int q = 0; q < JS; ++q) sum += part[q * HDC + c];
    int hh2 = c / C;
    float v = sum / dns[hh2] + bias[c];
    if (RELU) v = fmaxf(v, 0.f);
    xout[(size_t)n * HDC + c] = v;
  }
}

// ---------------- pair relation head (hoisted pidx, 2-deep UV prefetch) ----------------
// UV bf16 [node][3072] (per node: 6 r x (U 256 | V 256)); U includes rb1.
// grid (P/128, 6); block 256 = 4 waves; 16-lane group per pair, 8 iters.
__global__ __launch_bounds__(256) void pair_rel_k(
    const short* __restrict__ UV, const int* __restrict__ pidx,
    const float* __restrict__ lng, const float* __restrict__ lnb,
    const float* __restrict__ rW2, const float* __restrict__ rb2,
    float* __restrict__ out) {
  int t = threadIdx.x;
  int r = blockIdx.y;
  int w = t >> 6, lane = t & 63;
  int pg = lane >> 4, l16 = lane & 15;
  float g[16], bb[16], wv[16];
  int cb = r * 256 + l16 * 16;
#pragma unroll
  for (int q = 0; q < 4; ++q) {
    *(float4*)&g[q * 4]  = *(const float4*)&lng[cb + q * 4];
    *(float4*)&bb[q * 4] = *(const float4*)&lnb[cb + q * 4];
    *(float4*)&wv[q * 4] = *(const float4*)&rW2[cb + q * 4];
  }
  float rb2v = rb2[r];
  size_t roff = (size_t)r * 512 + l16 * 16;
  int pbase = blockIdx.x * 128 + w * 32;
  // hoist all 8 pidx loads (independent, coalesced)
  int2 ijs[8];
#pragma unroll
  for (int it = 0; it < 8; ++it)
    ijs[it] = *(const int2*)&pidx[2 * (pbase + it * 4 + pg)];
  // 2-deep register double-buffer of UV fragments
  bf16x8 u0[2], u1[2], v0[2], v1[2];
#pragma unroll
  for (int s = 0; s < 2; ++s) {
    const short* up = &UV[(size_t)ijs[s].x * 3072 + roff];
    const short* vp = &UV[(size_t)ijs[s].y * 3072 + roff + 256];
    u0[s] = *(const bf16x8*)up; u1[s] = *(const bf16x8*)(up + 8);
    v0[s] = *(const bf16x8*)vp; v1[s] = *(const bf16x8*)(vp + 8);
  }
#pragma unroll
  for (int it = 0; it < 8; ++it) {
    int b = it & 1;
    bf16x8 cu0 = u0[b], cu1 = u1[b], cv0 = v0[b], cv1 = v1[b];
    if (it + 2 < 8) {
      const short* up = &UV[(size_t)ijs[it + 2].x * 3072 + roff];
      const short* vp = &UV[(size_t)ijs[it + 2].y * 3072 + roff + 256];
      u0[b] = *(const bf16x8*)up; u1[b] = *(const bf16x8*)(up + 8);
      v0[b] = *(const bf16x8*)vp; v1[b] = *(const bf16x8*)(vp + 8);
    }
    float hv[16], s1 = 0.f, s2 = 0.f;
#pragma unroll
    for (int cc = 0; cc < 8; ++cc) {
      float h = bf2f(cu0[cc]) + bf2f(cv0[cc]);
      hv[cc] = h; s1 += h; s2 += h * h;
    }
#pragma unroll
    for (int cc = 0; cc < 8; ++cc) {
      float h = bf2f(cu1[cc]) + bf2f(cv1[cc]);
      hv[8 + cc] = h; s1 += h; s2 += h * h;
    }
#pragma unroll
    for (int off = 1; off < 16; off <<= 1) {
      s1 += __shfl_xor(s1, off, 64);
      s2 += __shfl_xor(s2, off, 64);
    }
    float mu = s1 * (1.f / 256.f);
    float var = s2 * (1.f / 256.f) - mu * mu;
    float rs = rsqrtf(var + 1e-5f);
    float pv = 0.f;
#pragma unroll
    for (int cc = 0; cc < 16; ++cc) {
      float v = (hv[cc] - mu) * rs * g[cc] + bb[cc];
      v = fmaxf(v, 0.f);
      pv += v * wv[cc];
    }
#pragma unroll
    for (int off = 1; off < 16; off <<= 1) pv += __shfl_xor(pv, off, 64);
    if (l16 == 0) out[(size_t)r * Pn + pbase + it * 4 + pg] = pv + rb2v;
  }
}

extern "C" void kernel_launch(void* const* d_in, const int* in_sizes, int n_in,
                              void* d_out, int out_size, void* d_ws, size_t ws_size,
                              hipStream_t stream) {
  const float* seq = (const float*)d_in[0];
  const int* est = (const int*)d_in[1];
  const int* eln = (const int*)d_in[2];
  const int* ebt = (const int*)d_in[3];
  const int* eidx = (const int*)d_in[4];
  const int* pidx = (const int*)d_in[5];
  const float* W1 = (const float*)d_in[6];
  const float* as1 = (const float*)d_in[7];
  const float* ad1 = (const float*)d_in[8];
  const float* b1 = (const float*)d_in[9];
  const float* W2 = (const float*)d_in[10];
  const float* as2 = (const float*)d_in[11];
  const float* ad2 = (const float*)d_in[12];
  const float* b2 = (const float*)d_in[13];
  const float* rW1 = (const float*)d_in[14];
  const float* rb1 = (const float*)d_in[15];
  const float* lng = (const float*)d_in[16];
  const float* lnb = (const float*)d_in[17];
  const float* rW2 = (const float*)d_in[18];
  const float* rb2 = (const float*)d_in[19];
  const float* nW1 = (const float*)d_in[20];
  const float* nb1 = (const float*)d_in[21];
  const float* nW2 = (const float*)d_in[22];
  const float* nb2 = (const float*)d_in[23];
  float* out = (float*)d_out;
  float* ws = (float*)d_ws;

  float* x0 = ws + OFF_X0;
  short* uv = (short*)(ws + OFF_UV);
  short* h1 = (short*)(ws + OFF_H1);
  float* x1 = ws + OFF_X1;
  short* h2 = (short*)(ws + OFF_H2);
  short* uvw = (short*)(ws + OFF_H2);   // after agg2/coef2, h2 region reused
  float* x2 = ws + OFF_X2;
  float* es1 = ws + OFF_ES1;
  float* ed1 = ws + OFF_ED1;
  float* es2 = ws + OFF_ES2;
  float* ed2 = ws + OFF_ED2;
  int* rowoff = (int*)(ws + OFF_ROW);
  int* cur = (int*)(ws + OFF_CUR);
  int* edg = (int*)(ws + OFF_EDG);
  short* w1s = (short*)(ws + OFF_W1S);
  short* nw1s = (short*)(ws + OFF_NW1S);
  short* w2s = (short*)(ws + OFF_W2S);

  // edge CSR build + merged weight swizzles
  zero_k<<<16, 256, 0, stream>>>(cur, Nn);
  count_k<<<(ET + 255) / 256, 256, 0, stream>>>(eidx, cur);
  scan_k<<<1, 256, 0, stream>>>(cur, rowoff);
  scatter_k<<<(ET + 255) / 256, 256, 0, stream>>>(eidx, cur, edg);
  swz_all_k<<<(768 * 512 + 768 * 256 + 512 * 64 + 255) / 256, 256, 0, stream>>>(
      W1, nW1, W2, w1s, nw1s, w2s);

  // entity features
  span_pool_k<<<Nn * (Hn / 4) / 256, 256, 0, stream>>>(seq, est, eln, ebt, x0);

  // GAT layer 1 (MFMA bf16, bf16 h1 out)
  mfma_gemm_k<2, 2, 128><<<dim3(Nn / 64, 512 / 128), 256, 0, stream>>>(x0, w1s, (float*)h1, nullptr, Nn, Hn, 512);
  coef_b_k<4, 128><<<(Nn * 4) / 256, 256, 0, stream>>>(h1, as1, ad1, es1, ed1);
  gat_agg_k<4, 128, true><<<Nn, 256, 0, stream>>>(h1, es1, ed1, rowoff, edg, b1, x1);

  // GAT layer 2 (MFMA bf16, bf16 h2 out)
  mfma_gemm_k<2, 1, 128><<<dim3(Nn / 64, 1), 256, 0, stream>>>(x1, w2s, (float*)h2, nullptr, Nn, 512, 64);
  coef_b_k<1, 64><<<(Nn + 255) / 256, 256, 0, stream>>>(h2, as2, ad2, es2, ed2);
  gat_agg_k<1, 64, false><<<Nn, 256, 0, stream>>>(h2, es2, ed2, rowoff, edg, b2, x2);

  // relation head: U/V node GEMM (+rb1 on U) then pair epilogue
  swz_uv_k<<<(6 * 128 * 256) / 256, 256, 0, stream>>>(rW1, uvw);
  mfma_gemm_k<4, 2, 64><<<dim3(Nn / 64, 3072 / 128), 256, 0, stream>>>(x2, uvw, (float*)uv, rb1, Nn, 64, 3072);
  pair_rel_k<<<dim3(Pn / 128, 6), 256, 0, stream>>>(uv, pidx, lng, lnb, rW2, rb2,
                                                    out + (size_t)Bn * Sn * 9);

  // fused NER head -> out[0 .. 147455]
  ner_fused_k<<<(Bn * Sn) / 64, 256, 0, stream>>>(seq, nw1s, nW2, nb1, nb2, out);
}